// Round 7
// baseline (501.947 us; speedup 1.0000x reference)
//
#include <hip/hip_runtime.h>
#include <math.h>

// BeliveMapsNMS: 7x7 same-padded max-pool NMS on [32,4,512,512] f32.
// Outputs (concat flat): mask(0/1 f32), scores_abs, scores_rel.
// R7: dense + continuous stores (the untested quadrant).
//   R5 proved strided NT stores amplify writes 1.58x and drain at ~2.4 TB/s.
//   R2/R6 proved dense-but-bursty (post-barrier) stores run ~3.2 TB/s.
//   The fill kernel proves dense+continuous runs 6.35 TB/s.
//   -> barrier-free, LDS-free wave-streaming with every load/store instruction
//      covering a dense 1 KB: lane k owns cols 4k..4k+3 (half A) and
//      256+4k..256+4k+3 (half B). Vertical van Herk in registers; horizontal
//      halo via intra-half shuffles; half-seam patched by 2 lane broadcasts.

#define H 512
#define W 512
#define PLANE_ELEMS (H * W)   // 262144
#define NEG_INF (-INFINITY)
#define VCHUNKS 32            // vmax chunks per plane

typedef float v4f __attribute__((ext_vector_type(4)));  // native vec for nontemporal

__device__ __forceinline__ float4 vmax4(float4 a, float4 b) {
    return make_float4(fmaxf(a.x, b.x), fmaxf(a.y, b.y), fmaxf(a.z, b.z), fmaxf(a.w, b.w));
}

__device__ __forceinline__ void nt_store4(float* p, float a, float b, float c, float d) {
    v4f v = {a, b, c, d};
    __builtin_nontemporal_store(v, (v4f*)p);
}

// ---------------- Pass 1: per-plane max (partials, no atomics) ----------------
__global__ __launch_bounds__(256) void vmax_kernel(const float* __restrict__ in,
                                                   float* __restrict__ partials) {
    const int chunk = blockIdx.x;  // 32 chunks of 8192 floats
    const int plane = blockIdx.y;  // 128 planes
    const float4* p = (const float4*)(in + (size_t)plane * PLANE_ELEMS) + chunk * 2048;
    float4 v[8];
    #pragma unroll
    for (int j = 0; j < 8; ++j) v[j] = p[threadIdx.x + (j << 8)];
    float4 t[4];
    #pragma unroll
    for (int j = 0; j < 4; ++j) t[j] = vmax4(v[j], v[j + 4]);
    float4 q = vmax4(vmax4(t[0], t[1]), vmax4(t[2], t[3]));
    float m = fmaxf(fmaxf(q.x, q.y), fmaxf(q.z, q.w));
    #pragma unroll
    for (int o = 32; o > 0; o >>= 1) m = fmaxf(m, __shfl_down(m, o, 64));
    __shared__ float s[4];
    if ((threadIdx.x & 63) == 0) s[threadIdx.x >> 6] = m;
    __syncthreads();
    if (threadIdx.x == 0) {
        partials[(plane << 5) + chunk] = fmaxf(fmaxf(s[0], s[1]), fmaxf(s[2], s[3]));
    }
}

// ---------------- Pass 2: NMS (barrier-free, dense streaming) ----------------
__global__ __launch_bounds__(256, 2) void nms_kernel(const float* __restrict__ in,
                                                     const float* __restrict__ partials,
                                                     float* __restrict__ out, int N) {
    // XCD-chunked swizzle: 2048 workgroups = 8 XCDs x 256 (bijective).
    const int hwid = blockIdx.x + (blockIdx.y << 4);   // gridDim.x = 16
    const int wg = ((hwid & 7) << 8) + (hwid >> 3);
    const int plane = wg >> 4;                          // 16 blocks per plane
    const int wid = threadIdx.x >> 6;
    const int lane = threadIdx.x & 63;
    const int band = ((wg & 15) << 2) + wid;            // 0..63, 8 rows each
    const int gy0 = band << 3;                          // first output row
    const int cA = lane << 2;                           // half A: cols 4k..4k+3

    const float* pin = in + (size_t)plane * PLANE_ELEMS;

    // 28 loads, every instruction dense (64 lanes x 16B contiguous).
    float4 rA[14], rB[14];
    #pragma unroll
    for (int k = 0; k < 14; ++k) {
        const int gy = gy0 + k - 3;
        const int gyc = gy < 0 ? 0 : (gy > H - 1 ? H - 1 : gy);
        const float* p = pin + (size_t)gyc * W;
        float4 a = *(const float4*)(p + cA);
        float4 b = *(const float4*)(p + 256 + cA);
        if (gy != gyc) {   // wave-uniform
            a = make_float4(NEG_INF, NEG_INF, NEG_INF, NEG_INF);
            b = make_float4(NEG_INF, NEG_INF, NEG_INF, NEG_INF);
        }
        rA[k] = a; rB[k] = b;
    }

    // Plane max from the 32 partials (broadcast).
    float4 pm[8];
    #pragma unroll
    for (int j = 0; j < 8; ++j) pm[j] = *(const float4*)&partials[(plane << 5) + (j << 2)];
    const float4 qq = vmax4(vmax4(vmax4(pm[0], pm[1]), vmax4(pm[2], pm[3])),
                            vmax4(vmax4(pm[4], pm[5]), vmax4(pm[6], pm[7])));
    const float vmax = fmaxf(fmaxf(qq.x, qq.y), fmaxf(qq.z, qq.w));
    const float rel_thr = 0.05f * vmax;
    const float inv_vmax = 1.0f / vmax;

    // Vertical suffix maxes over rows 0..6: AA[j] = max(r[j..6]).
    float4 AA[7], AB[7];
    AA[6] = rA[6]; AB[6] = rB[6];
    #pragma unroll
    for (int j = 5; j >= 0; --j) {
        AA[j] = vmax4(rA[j], AA[j + 1]);
        AB[j] = vmax4(rB[j], AB[j + 1]);
    }

    float* __restrict__ omask = out;
    float* __restrict__ oabs = out + (size_t)N;
    float* __restrict__ orel = out + 2 * (size_t)N;

    float4 BA, BB;
    #pragma unroll
    for (int i = 0; i < 8; ++i) {
        // vertical 7-max for output row i: max(r[i..i+6])
        float4 vA, vB;
        if (i == 0) {
            vA = AA[0]; vB = AB[0];
        } else {
            if (i == 1) { BA = rA[7]; BB = rB[7]; }
            else        { BA = vmax4(BA, rA[i + 6]); BB = vmax4(BB, rB[i + 6]); }
            if (i == 7) { vA = BA; vB = BB; }
            else        { vA = vmax4(AA[i], BA); vB = vmax4(AB[i], BB); }
        }

        // horizontal halos: neighbor lanes within each half; seam via broadcast.
        float lA0 = __shfl_up(vA.y, 1, 64), lA1 = __shfl_up(vA.z, 1, 64), lA2 = __shfl_up(vA.w, 1, 64);
        float rA0 = __shfl_down(vA.x, 1, 64), rA1 = __shfl_down(vA.y, 1, 64), rA2 = __shfl_down(vA.z, 1, 64);
        float lB0 = __shfl_up(vB.y, 1, 64), lB1 = __shfl_up(vB.z, 1, 64), lB2 = __shfl_up(vB.w, 1, 64);
        float rB0 = __shfl_down(vB.x, 1, 64), rB1 = __shfl_down(vB.y, 1, 64), rB2 = __shfl_down(vB.z, 1, 64);
        // seam values (wave-uniform broadcasts)
        const float sBx = __shfl(vB.x, 0, 64), sBy = __shfl(vB.y, 0, 64), sBz = __shfl(vB.z, 0, 64);
        const float sAy = __shfl(vA.y, 63, 64), sAz = __shfl(vA.z, 63, 64), sAw = __shfl(vA.w, 63, 64);
        if (lane == 0)  { lA0 = NEG_INF; lA1 = NEG_INF; lA2 = NEG_INF;
                          lB0 = sAy; lB1 = sAz; lB2 = sAw; }
        if (lane == 63) { rA0 = sBx; rA1 = sBy; rA2 = sBz;
                          rB0 = NEG_INF; rB1 = NEG_INF; rB2 = NEG_INF; }

        // horizontal 7-max per half: window a0..a9 = cols c-3..c+6
        float mA0, mA1, mA2, mA3, mB0, mB1, mB2, mB3;
        {
            const float a0 = lA0, a1 = lA1, a2 = lA2;
            const float a3 = vA.x, a4 = vA.y, a5 = vA.z, a6 = vA.w;
            const float a7 = rA0, a8 = rA1, a9 = rA2;
            const float t5 = fmaxf(a5, a6), t4 = fmaxf(a4, t5), t3 = fmaxf(a3, t4);
            const float t2 = fmaxf(a2, t3), t1 = fmaxf(a1, t2), t0 = fmaxf(a0, t1);
            const float b2 = fmaxf(a7, a8), b3 = fmaxf(b2, a9);
            mA0 = t0; mA1 = fmaxf(t1, a7); mA2 = fmaxf(t2, b2); mA3 = fmaxf(t3, b3);
        }
        {
            const float a0 = lB0, a1 = lB1, a2 = lB2;
            const float a3 = vB.x, a4 = vB.y, a5 = vB.z, a6 = vB.w;
            const float a7 = rB0, a8 = rB1, a9 = rB2;
            const float t5 = fmaxf(a5, a6), t4 = fmaxf(a4, t5), t3 = fmaxf(a3, t4);
            const float t2 = fmaxf(a2, t3), t1 = fmaxf(a1, t2), t0 = fmaxf(a0, t1);
            const float b2 = fmaxf(a7, a8), b3 = fmaxf(b2, a9);
            mB0 = t0; mB1 = fmaxf(t1, a7); mB2 = fmaxf(t2, b2); mB3 = fmaxf(t3, b3);
        }

        // centers already in registers
        const float4 cAv = rA[i + 3], cBv = rB[i + 3];
        const bool pA0 = (mA0 == cAv.x) & (cAv.x > 0.2f) & (cAv.x > rel_thr);
        const bool pA1 = (mA1 == cAv.y) & (cAv.y > 0.2f) & (cAv.y > rel_thr);
        const bool pA2 = (mA2 == cAv.z) & (cAv.z > 0.2f) & (cAv.z > rel_thr);
        const bool pA3 = (mA3 == cAv.w) & (cAv.w > 0.2f) & (cAv.w > rel_thr);
        const bool pB0 = (mB0 == cBv.x) & (cBv.x > 0.2f) & (cBv.x > rel_thr);
        const bool pB1 = (mB1 == cBv.y) & (cBv.y > 0.2f) & (cBv.y > rel_thr);
        const bool pB2 = (mB2 == cBv.z) & (cBv.z > 0.2f) & (cBv.z > rel_thr);
        const bool pB3 = (mB3 == cBv.w) & (cBv.w > 0.2f) & (cBv.w > rel_thr);
        const float sA0 = pA0 ? cAv.x : 0.0f, sA1 = pA1 ? cAv.y : 0.0f;
        const float sA2 = pA2 ? cAv.z : 0.0f, sA3 = pA3 ? cAv.w : 0.0f;
        const float sB0 = pB0 ? cBv.x : 0.0f, sB1 = pB1 ? cBv.y : 0.0f;
        const float sB2 = pB2 ? cBv.z : 0.0f, sB3 = pB3 ? cBv.w : 0.0f;

        const int gy = gy0 + i;
        const size_t o = (size_t)plane * PLANE_ELEMS + (size_t)gy * W + cA;
        const size_t o2 = o + 256;
        nt_store4(omask + o,  pA0 ? 1.0f : 0.0f, pA1 ? 1.0f : 0.0f,
                              pA2 ? 1.0f : 0.0f, pA3 ? 1.0f : 0.0f);
        nt_store4(omask + o2, pB0 ? 1.0f : 0.0f, pB1 ? 1.0f : 0.0f,
                              pB2 ? 1.0f : 0.0f, pB3 ? 1.0f : 0.0f);
        nt_store4(oabs + o,  sA0, sA1, sA2, sA3);
        nt_store4(oabs + o2, sB0, sB1, sB2, sB3);
        nt_store4(orel + o,  sA0 * inv_vmax, sA1 * inv_vmax, sA2 * inv_vmax, sA3 * inv_vmax);
        nt_store4(orel + o2, sB0 * inv_vmax, sB1 * inv_vmax, sB2 * inv_vmax, sB3 * inv_vmax);
    }
}

extern "C" void kernel_launch(void* const* d_in, const int* in_sizes, int n_in,
                              void* d_out, int out_size, void* d_ws, size_t ws_size,
                              hipStream_t stream) {
    const float* in = (const float*)d_in[0];
    float* out = (float*)d_out;
    const int N = in_sizes[0];           // 33554432
    const int planes = N / PLANE_ELEMS;  // 128

    float* partials = (float*)d_ws;      // 128*32 floats = 16 KB

    vmax_kernel<<<dim3(VCHUNKS, planes), 256, 0, stream>>>(in, partials);
    nms_kernel<<<dim3(16, planes), 256, 0, stream>>>(in, partials, out, N);
}

// Round 8
// 477.196 us; speedup vs baseline: 1.0519x; 1.0519x over previous
//
#include <hip/hip_runtime.h>
#include <math.h>

// BeliveMapsNMS: 7x7 same-padded max-pool NMS on [32,4,512,512] f32.
// Outputs (concat flat): mask(0/1 f32), scores_abs, scores_rel.
// R8: restore of R2 — the best harness-verified variant (477.06 us).
// Session findings (all A/B-measured on MI355X):
//  - NT stores beat cached stores by ~28 us (R4); dense 1KB/instr stores beat
//    32B-strided by ~150 us via 1.58x write-amplification (R5 counters).
//  - Effective store-path BW for this mixed read+3-stream-write workload is
//    pinned at ~2.5 TB/s across instruction type, density, ordering (R6),
//    schedule (R7), occupancy 8->20 waves, and read-side structure (R1/R3).
//    Pure-write fill hits 6.35 TB/s; the gap is structural, not controllable
//    from source. Timed region is dominated by the harness's 253 us poison
//    fill + this ~2.5 TB/s ceiling.
// Structure: TH=8 row-band per block; per-wave full-row horizontal 7-max via
// shuffle van Herk -> LDS; per-thread vertical 7-max van Herk from LDS;
// pre-barrier ctr prefetch; partials-based vmax (no memset/atomics);
// XCD-chunked bijective block swizzle; NT float4 stores.

#define H 512
#define W 512
#define PLANE_ELEMS (H * W)   // 262144
#define TH 8                  // output rows per block
#define LROWS (TH + 6)        // 14 loaded rows
#define NEG_INF (-INFINITY)
#define VCHUNKS 16            // vmax chunks per plane

typedef float v4f __attribute__((ext_vector_type(4)));  // native vec for nontemporal

__device__ __forceinline__ float4 vmax4(float4 a, float4 b) {
    return make_float4(fmaxf(a.x, b.x), fmaxf(a.y, b.y), fmaxf(a.z, b.z), fmaxf(a.w, b.w));
}

__device__ __forceinline__ void nt_store4(float* p, float a, float b, float c, float d) {
    v4f v = {a, b, c, d};
    __builtin_nontemporal_store(v, (v4f*)p);
}

// ---------------- Pass 1: per-plane max (partials, no atomics) ----------------
__global__ __launch_bounds__(256) void vmax_kernel(const float* __restrict__ in,
                                                   float* __restrict__ partials) {
    const int chunk = blockIdx.x;  // 16 chunks of 16384 floats
    const int plane = blockIdx.y;  // 128 planes
    const float4* p = (const float4*)(in + (size_t)plane * PLANE_ELEMS) + chunk * 4096;
    // 16 independent float4 loads per thread, fully unrolled -> deep MLP.
    float4 v[16];
    #pragma unroll
    for (int j = 0; j < 16; ++j) v[j] = p[threadIdx.x + (j << 8)];
    float4 t[8];
    #pragma unroll
    for (int j = 0; j < 8; ++j) t[j] = vmax4(v[j], v[j + 8]);
    #pragma unroll
    for (int j = 0; j < 4; ++j) t[j] = vmax4(t[j], t[j + 4]);
    float4 q = vmax4(vmax4(t[0], t[1]), vmax4(t[2], t[3]));
    float m = fmaxf(fmaxf(q.x, q.y), fmaxf(q.z, q.w));
    #pragma unroll
    for (int o = 32; o > 0; o >>= 1) m = fmaxf(m, __shfl_down(m, o, 64));
    __shared__ float s[4];
    if ((threadIdx.x & 63) == 0) s[threadIdx.x >> 6] = m;
    __syncthreads();
    if (threadIdx.x == 0) {
        // inputs non-negative; every slot written each launch -> no init needed
        partials[(plane << 4) + chunk] = fmaxf(fmaxf(s[0], s[1]), fmaxf(s[2], s[3]));
    }
}

// ---------------- Pass 2: NMS ----------------
__global__ __launch_bounds__(256, 4) void nms_kernel(const float* __restrict__ in,
                                                     const float* __restrict__ partials,
                                                     float* __restrict__ out, int N) {
    // XCD-chunked swizzle: 8192 workgroups = 8 XCDs x 1024 (bijective, 8192%8==0).
    const int hwid = blockIdx.x + (blockIdx.y << 6);     // gridDim.x = 64 bands
    const int wg = ((hwid & 7) << 10) + (hwid >> 3);
    const int plane = wg >> 6;
    const int ty0 = (wg & 63) * TH;

    const float* pin = in + (size_t)plane * PLANE_ELEMS;

    __shared__ __align__(16) float sRow[LROWS * W];  // 28672 B -> 4-5 blocks/CU

    const int wid = threadIdx.x >> 6;   // wave 0..3
    const int lane = threadIdx.x & 63;
    const int c8 = lane << 3;           // 8 columns per lane; one wave = one full row

    // Plane max from the 16 partials (one cacheline, broadcast; issued early).
    float pm[16];
    #pragma unroll
    for (int j = 0; j < 16; ++j) pm[j] = partials[(plane << 4) + j];

    // Phase A0: issue all row loads up front (independent dwordx4's).
    float4 va[4], vb[4];
    #pragma unroll
    for (int k = 0; k < 4; ++k) {
        const int r = wid + (k << 2);
        if (r < LROWS) {
            const int gy = ty0 + r - 3;
            if (gy >= 0 && gy < H) {
                const float4* row = (const float4*)(pin + (size_t)gy * W);
                va[k] = row[lane * 2];
                vb[k] = row[lane * 2 + 1];
            } else {
                va[k] = vb[k] = make_float4(NEG_INF, NEG_INF, NEG_INF, NEG_INF);
            }
        }
    }

    // Phase A1: horizontal 7-max entirely in registers (shuffle halo).
    #pragma unroll
    for (int k = 0; k < 4; ++k) {
        const int r = wid + (k << 2);
        if (r < LROWS) {   // wave-uniform guard: shuffles below are safe
            float4 v0 = va[k], v1 = vb[k];
            float l0 = __shfl_up(v1.y, 1, 64), l1 = __shfl_up(v1.z, 1, 64), l2 = __shfl_up(v1.w, 1, 64);
            float r0 = __shfl_down(v0.x, 1, 64), r1 = __shfl_down(v0.y, 1, 64), r2 = __shfl_down(v0.z, 1, 64);
            if (lane == 0) { l0 = NEG_INF; l1 = NEG_INF; l2 = NEG_INF; }
            if (lane == 63) { r0 = NEG_INF; r1 = NEG_INF; r2 = NEG_INF; }
            float a[14] = {l0, l1, l2, v0.x, v0.y, v0.z, v0.w, v1.x, v1.y, v1.z, v1.w, r0, r1, r2};
            // van Herk: rm[j] = max(a[j..j+6]), j=0..7; split at a[7]
            float A[7];
            A[6] = a[6];
            #pragma unroll
            for (int j = 5; j >= 0; --j) A[j] = fmaxf(a[j], A[j + 1]);
            float rm[8];
            rm[0] = A[0];
            float B = a[7];
            rm[1] = fmaxf(A[1], B);
            #pragma unroll
            for (int j = 2; j <= 6; ++j) { B = fmaxf(B, a[6 + j]); rm[j] = fmaxf(A[j], B); }
            B = fmaxf(B, a[13]);
            rm[7] = B;
            float4* dst = (float4*)&sRow[r * W + c8];
            dst[0] = make_float4(rm[0], rm[1], rm[2], rm[3]);
            dst[1] = make_float4(rm[4], rm[5], rm[6], rm[7]);
        }
    }

    // Phase B thread mapping.
    const int strip = threadIdx.x >> 7;       // 0/1 -> rows 0..3 / 4..7
    const int cg = threadIdx.x & 127;
    const int c = cg << 2;
    const int y0 = strip << 2;
    const int gy_base = ty0 + y0;

    // Prefetch center values BEFORE the barrier (L3/L2-hot after vmax pass).
    float4 ctr[4];
    #pragma unroll
    for (int i = 0; i < 4; ++i) {
        ctr[i] = *(const float4*)(pin + (size_t)(gy_base + i) * W + c);
    }

    // Reduce plane max (exact: fmax over disjoint chunks).
    float vmax = pm[0];
    #pragma unroll
    for (int j = 1; j < 16; ++j) vmax = fmaxf(vmax, pm[j]);
    const float rel_thr = 0.05f * vmax;
    const float inv_vmax = 1.0f / vmax;

    __syncthreads();

    float* __restrict__ omask = out;
    float* __restrict__ oabs = out + (size_t)N;
    float* __restrict__ orel = out + 2 * (size_t)N;

    // Phase B: vertical 7-max (van Herk over 10 rows -> 4 outputs per thread).
    float4 Lr[7];
    #pragma unroll
    for (int k = 0; k < 7; ++k) Lr[k] = *(const float4*)&sRow[(y0 + k) * W + c];
    float4 Aq[4];
    {
        float4 suf = vmax4(Lr[4], vmax4(Lr[5], Lr[6]));
        Aq[3] = vmax4(Lr[3], suf);
        Aq[2] = vmax4(Lr[2], Aq[3]);
        Aq[1] = vmax4(Lr[1], Aq[2]);
        Aq[0] = vmax4(Lr[0], Aq[1]);
    }

    float4 Bq;
    #pragma unroll
    for (int i = 0; i < 4; ++i) {
        float4 m;
        if (i == 0) {
            m = Aq[0];
        } else {
            float4 row = *(const float4*)&sRow[(y0 + 6 + i) * W + c];
            Bq = (i == 1) ? row : vmax4(Bq, row);
            m = vmax4(Aq[i], Bq);
        }
        const int gy = gy_base + i;
        const float4 cc = ctr[i];
        const bool p0 = (m.x == cc.x) & (cc.x > 0.2f) & (cc.x > rel_thr);
        const bool p1 = (m.y == cc.y) & (cc.y > 0.2f) & (cc.y > rel_thr);
        const bool p2 = (m.z == cc.z) & (cc.z > 0.2f) & (cc.z > rel_thr);
        const bool p3 = (m.w == cc.w) & (cc.w > 0.2f) & (cc.w > rel_thr);
        const float a0 = p0 ? cc.x : 0.0f, a1 = p1 ? cc.y : 0.0f;
        const float a2 = p2 ? cc.z : 0.0f, a3 = p3 ? cc.w : 0.0f;
        const size_t o = (size_t)plane * PLANE_ELEMS + (size_t)gy * W + c;
        nt_store4(omask + o, p0 ? 1.0f : 0.0f, p1 ? 1.0f : 0.0f,
                             p2 ? 1.0f : 0.0f, p3 ? 1.0f : 0.0f);
        nt_store4(oabs + o, a0, a1, a2, a3);
        nt_store4(orel + o, a0 * inv_vmax, a1 * inv_vmax,
                            a2 * inv_vmax, a3 * inv_vmax);
    }
}

extern "C" void kernel_launch(void* const* d_in, const int* in_sizes, int n_in,
                              void* d_out, int out_size, void* d_ws, size_t ws_size,
                              hipStream_t stream) {
    const float* in = (const float*)d_in[0];
    float* out = (float*)d_out;
    const int N = in_sizes[0];           // 33554432
    const int planes = N / PLANE_ELEMS;  // 128

    float* partials = (float*)d_ws;      // 128*16 floats = 8 KB

    vmax_kernel<<<dim3(VCHUNKS, planes), 256, 0, stream>>>(in, partials);
    nms_kernel<<<dim3(H / TH, planes), 256, 0, stream>>>(in, partials, out, N);
}